// Round 1
// baseline (302.218 us; speedup 1.0000x reference)
//
#include <hip/hip_runtime.h>
#include <math.h>

#define Nn 512
#define Tt 8
#define Ee 16384
#define NNc (Nn*Nn)          // 262144
#define TNr (Tt*Nn)          // 4096

// ---------------- feat_proj: [T*N,128] -> relu -> [.,256] -> relu -> [.,64] ; concat noise -> emb[.,80]
__global__ __launch_bounds__(256) void k_featproj(
    const float* __restrict__ feats, const float* __restrict__ noise,
    const float* __restrict__ Wp1, const float* __restrict__ bp1,
    const float* __restrict__ Wp2, const float* __restrict__ bp2,
    float* __restrict__ emb)
{
    __shared__ float sfeat[16][128];
    __shared__ float sh1[16][256];
    int tid = threadIdx.x;
    int r0 = blockIdx.x * 16;
#pragma unroll
    for (int k = 0; k < 8; ++k) {
        int lin = k*256 + tid;
        sfeat[lin>>7][lin&127] = feats[(size_t)r0*128 + lin];
    }
    __syncthreads();
    // h1: 256 outputs, one per thread, 16 rows each
    {
        int j = tid;
        float acc[16];
#pragma unroll
        for (int r=0;r<16;++r) acc[r]=0.f;
        for (int i=0;i<128;i+=4) {
            float w0=Wp1[(i+0)*256+j], w1=Wp1[(i+1)*256+j];
            float w2=Wp1[(i+2)*256+j], w3=Wp1[(i+3)*256+j];
#pragma unroll
            for (int r=0;r<16;++r) {
                float4 f = *(const float4*)&sfeat[r][i];
                acc[r] += f.x*w0 + f.y*w1 + f.z*w2 + f.w*w3;
            }
        }
        float b = bp1[j];
#pragma unroll
        for (int r=0;r<16;++r) sh1[r][j] = fmaxf(acc[r]+b, 0.f);
    }
    __syncthreads();
    // h2: 64 outputs x 16 rows
    {
        int jo = tid & 63;
        int rr = tid >> 6;           // 0..3
        float b2v = bp2[jo];
        for (int rg=0; rg<4; ++rg) {
            int r = rg*4 + rr;
            float a2 = 0.f;
            for (int i=0;i<256;i+=4) {
                float4 f = *(const float4*)&sh1[r][i];
                a2 += f.x*Wp2[(i+0)*64+jo] + f.y*Wp2[(i+1)*64+jo]
                    + f.z*Wp2[(i+2)*64+jo] + f.w*Wp2[(i+3)*64+jo];
            }
            emb[(size_t)(r0+r)*80 + jo] = fmaxf(a2+b2v, 0.f);
        }
    }
    // noise passthrough
    {
        int r = tid>>4, k = tid&15;
        emb[(size_t)(r0+r)*80 + 64 + k] = noise[(size_t)(r0+r)*16 + k];
    }
}

// ---------------- hh = relu(emb @ W1[80,128] + b1)
__global__ __launch_bounds__(256) void k_wle1(
    const float* __restrict__ emb, const float* __restrict__ W1,
    const float* __restrict__ b1, float* __restrict__ hh)
{
    __shared__ float semb[16][80];
    int tid = threadIdx.x;
    int r0 = blockIdx.x*16;
#pragma unroll
    for (int k=0;k<5;++k) {
        int lin = k*256+tid;            // 0..1279
        semb[lin/80][lin%80] = emb[(size_t)r0*80 + lin];
    }
    __syncthreads();
    int j = tid & 127;
    int rb = (tid>>7)*8;
    float acc[8];
#pragma unroll
    for (int r=0;r<8;++r) acc[r]=0.f;
    for (int i=0;i<80;i+=4) {
        float w0=W1[(i+0)*128+j], w1=W1[(i+1)*128+j];
        float w2=W1[(i+2)*128+j], w3=W1[(i+3)*128+j];
#pragma unroll
        for (int r=0;r<8;++r) {
            float4 f = *(const float4*)&semb[rb+r][i];
            acc[r] += f.x*w0 + f.y*w1 + f.z*w2 + f.w*w3;
        }
    }
    float b = b1[j];
#pragma unroll
    for (int r=0;r<8;++r) hh[(size_t)(r0+rb+r)*128 + j] = fmaxf(acc[r]+b, 0.f);
}

// ---------------- msg scatter: agg[dst] += ew * hh[src]
__global__ __launch_bounds__(256) void k_scatter(
    const int* __restrict__ ei, const float* __restrict__ ew,
    const float* __restrict__ hh, float* __restrict__ agg)
{
    size_t g = (size_t)blockIdx.x*256 + threadIdx.x;   // < T*E*128
    int ch = (int)(g & 127);
    int eg = (int)(g >> 7);        // t*E+e
    int t = eg >> 14;
    int e = eg & (Ee-1);
    int dst = ei[t*2*Ee + e];
    int src = ei[t*2*Ee + Ee + e];
    float w = ew[eg];
    float v = w * hh[((size_t)(t*Nn+src))*128 + ch];
    atomicAdd(&agg[((size_t)(t*Nn+dst))*128 + ch], v);
}

// ---------------- h2 = relu((hh+agg) @ W2[128,128] + b2)
__global__ __launch_bounds__(256) void k_wle2(
    const float* __restrict__ hh, const float* __restrict__ agg,
    const float* __restrict__ W2, const float* __restrict__ b2,
    float* __restrict__ h2)
{
    __shared__ float sx[16][128];
    int tid=threadIdx.x; int r0=blockIdx.x*16;
#pragma unroll
    for (int k=0;k<8;++k){
        int lin=k*256+tid;
        size_t gidx=(size_t)r0*128+lin;
        sx[lin>>7][lin&127]=hh[gidx]+agg[gidx];
    }
    __syncthreads();
    int j=tid&127; int rb=(tid>>7)*8;
    float acc[8];
#pragma unroll
    for(int r=0;r<8;++r)acc[r]=0.f;
    for(int i=0;i<128;i+=4){
        float w0=W2[(i+0)*128+j], w1=W2[(i+1)*128+j];
        float w2v=W2[(i+2)*128+j], w3=W2[(i+3)*128+j];
#pragma unroll
        for(int r=0;r<8;++r){
            float4 f=*(const float4*)&sx[rb+r][i];
            acc[r]+=f.x*w0+f.y*w1+f.z*w2v+f.w*w3;
        }
    }
    float b=b2[j];
#pragma unroll
    for(int r=0;r<8;++r) h2[(size_t)(r0+rb+r)*128+j]=fmaxf(acc[r]+b,0.f);
}

// ---------------- edge scores: s = relu((h2[a]*h2[b]) @ W3) . w4 + b4
#define EPB 256   // edges per block
__global__ __launch_bounds__(256) void k_edge(
    const int* __restrict__ ei, const float* __restrict__ h2,
    const float* __restrict__ W3, const float* __restrict__ b3,
    const float* __restrict__ w4, const float* __restrict__ b4,
    float* __restrict__ sc)
{
    __shared__ float sW3[128*128];
    __shared__ float sef[128][8];
    __shared__ float sred[2][2][4];
    int tid = threadIdx.x;
#pragma unroll
    for (int k=0;k<64;++k) sW3[k*256+tid] = W3[k*256+tid];
    int j = tid & 127, g = tid >> 7;
    float bj = b3[j], wj = w4[j];
    float b4v = b4[0];
    int ebase = blockIdx.x * EPB;
    for (int it=0; it<EPB/8; ++it) {
        int e8 = ebase + it*8;
        __syncthreads();
        // load 8 edges' ef (transposed: sef[i][edge])
#pragma unroll
        for (int k=0;k<4;++k){
            int lin = k*256+tid;
            int el = lin>>7, i = lin&127;
            int eg = e8 + el;
            int t = eg>>14, e = eg&(Ee-1);
            int a = ei[t*2*Ee + e], b = ei[t*2*Ee + Ee + e];
            float va = h2[((size_t)(t*Nn+a))*128 + i];
            float vb = h2[((size_t)(t*Nn+b))*128 + i];
            sef[i][el] = va*vb;
        }
        __syncthreads();
        float a0=0.f,a1=0.f,a2=0.f,a3=0.f;
        for (int i=0;i<128;++i){
            float w = sW3[i*128+j];
            float4 f = *(const float4*)&sef[i][g*4];
            a0 += f.x*w; a1 += f.y*w; a2 += f.z*w; a3 += f.w*w;
        }
        float v0 = fmaxf(a0+bj,0.f)*wj;
        float v1 = fmaxf(a1+bj,0.f)*wj;
        float v2 = fmaxf(a2+bj,0.f)*wj;
        float v3 = fmaxf(a3+bj,0.f)*wj;
#pragma unroll
        for (int off=32; off>0; off>>=1){
            v0 += __shfl_xor(v0,off);
            v1 += __shfl_xor(v1,off);
            v2 += __shfl_xor(v2,off);
            v3 += __shfl_xor(v3,off);
        }
        if ((tid&63)==0){
            int wv = (tid>>6)&1;
            sred[g][wv][0]=v0; sred[g][wv][1]=v1; sred[g][wv][2]=v2; sred[g][wv][3]=v3;
        }
        __syncthreads();
        if (tid<8){
            int gg=tid>>2, r=tid&3;
            sc[e8+gg*4+r] = sred[gg][0][r]+sred[gg][1][r]+b4v;
        }
    }
}

// ---------------- densify with last-write-wins: tag pass then write pass
__global__ __launch_bounds__(256) void k_tag(const int* __restrict__ ei, int* __restrict__ tag)
{
    int g = blockIdx.x*256+threadIdx.x;        // < T*E
    int t = g>>14, e = g&(Ee-1);
    int a = ei[t*2*Ee + e], b = ei[t*2*Ee + Ee + e];
    atomicMax(&tag[t*NNc + a*Nn + b], g+1);
}

__global__ __launch_bounds__(256) void k_dense(
    const int* __restrict__ ei, const float* __restrict__ sc,
    const int* __restrict__ tag, float* __restrict__ dense)
{
    int g = blockIdx.x*256+threadIdx.x;
    int t = g>>14, e = g&(Ee-1);
    int a = ei[t*2*Ee + e], b = ei[t*2*Ee + Ee + e];
    int cell = t*NNc + a*Nn + b;
    if (tag[cell] == g+1) dense[cell] = sc[g];
}

// ---------------- SSM recurrence: only cells with an edge at t=T-1 have nonzero output
__global__ __launch_bounds__(256) void k_ssm(
    const int* __restrict__ ei, const float* __restrict__ dense,
    const float* __restrict__ W_in, const float* __restrict__ conv_w,
    const float* __restrict__ conv_b, const float* __restrict__ dt_bias,
    const float* __restrict__ A_log, const float* __restrict__ D_skip,
    const float* __restrict__ W_out, float* __restrict__ out)
{
    __shared__ float scw[132], scb[33], swin[35];
    int tid = threadIdx.x;
    if (tid < 132) scw[tid] = conv_w[tid];
    if (tid < 33)  scb[tid] = conv_b[tid];
    if (tid < 35)  swin[tid] = W_in[tid];
    __syncthreads();

    int e = blockIdx.x*256 + tid;              // < E
    int a = ei[7*2*Ee + e], b = ei[7*2*Ee + Ee + e];
    int cell = a*Nn + b;
    float x[8];
#pragma unroll
    for (int t=0;t<8;++t) x[t] = dense[t*NNc + cell];

    float A    = -expf(A_log[0]);
    float dtb  = dt_bias[0];
    float dsk  = D_skip[0];
    float wout = W_out[0];
    float win_z = swin[0], win_dt = swin[34];

    float ssm[16];
#pragma unroll
    for (int q=0;q<16;++q) ssm[q]=0.f;
    float h0=0.f,h1=0.f,h2v=0.f;   // x_{t-3}, x_{t-2}, x_{t-1}
    float y=0.f;
    for (int t=0;t<8;++t){
        float xt = x[t];
        float act[33];
#pragma unroll
        for (int c=0;c<33;++c){
            float s = h0*scw[c*4+0] + h1*scw[c*4+1] + h2v*scw[c*4+2] + xt*scw[c*4+3];
            float pre = swin[1+c]*s + scb[c];
            act[c] = pre / (1.f + expf(-pre));          // silu
        }
        float x_ = act[0];
        float dtr = xt*win_dt + dtb;
        float dt  = (dtr > 20.f) ? dtr : log1pf(expf(dtr));  // softplus
        float dA  = expf(dt*A);
        float dx  = dt*x_;
        float yv = 0.f;
#pragma unroll
        for (int q=0;q<16;++q){
            ssm[q] = ssm[q]*dA + dx*act[1+q];
            yv += ssm[q]*act[17+q];
        }
        yv += dsk*x_;
        float z = xt*win_z;
        yv *= z / (1.f + expf(-z));
        y = yv;
        h0=h1; h1=h2v; h2v=xt;
    }
    out[cell] = y*wout;
}

extern "C" void kernel_launch(void* const* d_in, const int* in_sizes, int n_in,
                              void* d_out, int out_size, void* d_ws, size_t ws_size,
                              hipStream_t stream)
{
    const int*   ei    = (const int*)d_in[0];
    const float* ew    = (const float*)d_in[1];
    const float* feats = (const float*)d_in[2];
    const float* noise = (const float*)d_in[3];
    const float* Wp1=(const float*)d_in[4];  const float* bp1=(const float*)d_in[5];
    const float* Wp2=(const float*)d_in[6];  const float* bp2=(const float*)d_in[7];
    const float* W1 =(const float*)d_in[8];  const float* b1 =(const float*)d_in[9];
    const float* W2 =(const float*)d_in[10]; const float* b2 =(const float*)d_in[11];
    const float* W3 =(const float*)d_in[12]; const float* b3 =(const float*)d_in[13];
    const float* w4 =(const float*)d_in[14]; const float* b4 =(const float*)d_in[15];
    const float* W_in  =(const float*)d_in[16]; const float* conv_w=(const float*)d_in[17];
    const float* conv_b=(const float*)d_in[18]; const float* dt_bias=(const float*)d_in[19];
    const float* A_log =(const float*)d_in[20]; const float* D_skip=(const float*)d_in[21];
    const float* W_out =(const float*)d_in[22];

    float* out = (float*)d_out;
    float* ws  = (float*)d_ws;
    float* emb   = ws;                   // T*N*80   = 327680
    float* hh    = emb   + 327680;       // T*N*128  = 524288
    float* agg   = hh    + 524288;       // 524288
    float* h2    = agg   + 524288;       // 524288
    float* sc    = h2    + 524288;       // T*E      = 131072
    float* dense = sc    + 131072;       // T*N*N    = 2097152
    int*   tag   = (int*)(dense + 2097152); // T*N*N ints

    hipMemsetAsync(agg,   0, (size_t)524288*4,  stream);
    hipMemsetAsync(dense, 0, (size_t)2097152*4, stream);
    hipMemsetAsync(tag,   0, (size_t)2097152*4, stream);
    hipMemsetAsync(out,   0, (size_t)262144*4,  stream);

    k_featproj<<<TNr/16, 256, 0, stream>>>(feats, noise, Wp1, bp1, Wp2, bp2, emb);
    k_wle1   <<<TNr/16, 256, 0, stream>>>(emb, W1, b1, hh);
    k_scatter<<<(Tt*Ee*128)/256, 256, 0, stream>>>(ei, ew, hh, agg);
    k_wle2   <<<TNr/16, 256, 0, stream>>>(hh, agg, W2, b2, h2);
    k_edge   <<<(Tt*Ee)/EPB, 256, 0, stream>>>(ei, h2, W3, b3, w4, b4, sc);
    k_tag    <<<(Tt*Ee)/256, 256, 0, stream>>>(ei, tag);
    k_dense  <<<(Tt*Ee)/256, 256, 0, stream>>>(ei, sc, tag, dense);
    k_ssm    <<<Ee/256, 256, 0, stream>>>(ei, dense, W_in, conv_w, conv_b,
                                          dt_bias, A_log, D_skip, W_out, out);
}

// Round 2
// 297.111 us; speedup vs baseline: 1.0172x; 1.0172x over previous
//
#include <hip/hip_runtime.h>
#include <math.h>

#define Nn 512
#define Tt 8
#define Ee 16384
#define NNc (Nn*Nn)          // 262144
#define TNr (Tt*Nn)          // 4096
#define TE  (Tt*Ee)          // 131072

// ---------------- feat_proj: [T*N,128] -> relu -> [.,256] -> relu -> [.,64] ; concat noise -> emb[.,80]
__global__ __launch_bounds__(256) void k_featproj(
    const float* __restrict__ feats, const float* __restrict__ noise,
    const float* __restrict__ Wp1, const float* __restrict__ bp1,
    const float* __restrict__ Wp2, const float* __restrict__ bp2,
    float* __restrict__ emb)
{
    __shared__ float sfeat[16][128];
    __shared__ float sh1[16][256];
    int tid = threadIdx.x;
    int r0 = blockIdx.x * 16;
#pragma unroll
    for (int k = 0; k < 8; ++k) {
        int lin = k*256 + tid;
        sfeat[lin>>7][lin&127] = feats[(size_t)r0*128 + lin];
    }
    __syncthreads();
    {
        int j = tid;
        float acc[16];
#pragma unroll
        for (int r=0;r<16;++r) acc[r]=0.f;
        for (int i=0;i<128;i+=4) {
            float w0=Wp1[(i+0)*256+j], w1=Wp1[(i+1)*256+j];
            float w2=Wp1[(i+2)*256+j], w3=Wp1[(i+3)*256+j];
#pragma unroll
            for (int r=0;r<16;++r) {
                float4 f = *(const float4*)&sfeat[r][i];
                acc[r] += f.x*w0 + f.y*w1 + f.z*w2 + f.w*w3;
            }
        }
        float b = bp1[j];
#pragma unroll
        for (int r=0;r<16;++r) sh1[r][j] = fmaxf(acc[r]+b, 0.f);
    }
    __syncthreads();
    {
        int jo = tid & 63;
        int rr = tid >> 6;
        float b2v = bp2[jo];
        for (int rg=0; rg<4; ++rg) {
            int r = rg*4 + rr;
            float a2 = 0.f;
            for (int i=0;i<256;i+=4) {
                float4 f = *(const float4*)&sh1[r][i];
                a2 += f.x*Wp2[(i+0)*64+jo] + f.y*Wp2[(i+1)*64+jo]
                    + f.z*Wp2[(i+2)*64+jo] + f.w*Wp2[(i+3)*64+jo];
            }
            emb[(size_t)(r0+r)*80 + jo] = fmaxf(a2+b2v, 0.f);
        }
    }
    {
        int r = tid>>4, k = tid&15;
        emb[(size_t)(r0+r)*80 + 64 + k] = noise[(size_t)(r0+r)*16 + k];
    }
}

// ---------------- hh = relu(emb @ W1[80,128] + b1)
__global__ __launch_bounds__(256) void k_wle1(
    const float* __restrict__ emb, const float* __restrict__ W1,
    const float* __restrict__ b1, float* __restrict__ hh)
{
    __shared__ float semb[16][80];
    int tid = threadIdx.x;
    int r0 = blockIdx.x*16;
#pragma unroll
    for (int k=0;k<5;++k) {
        int lin = k*256+tid;
        semb[lin/80][lin%80] = emb[(size_t)r0*80 + lin];
    }
    __syncthreads();
    int j = tid & 127;
    int rb = (tid>>7)*8;
    float acc[8];
#pragma unroll
    for (int r=0;r<8;++r) acc[r]=0.f;
    for (int i=0;i<80;i+=4) {
        float w0=W1[(i+0)*128+j], w1=W1[(i+1)*128+j];
        float w2=W1[(i+2)*128+j], w3=W1[(i+3)*128+j];
#pragma unroll
        for (int r=0;r<8;++r) {
            float4 f = *(const float4*)&semb[rb+r][i];
            acc[r] += f.x*w0 + f.y*w1 + f.z*w2 + f.w*w3;
        }
    }
    float b = b1[j];
#pragma unroll
    for (int r=0;r<8;++r) hh[(size_t)(r0+rb+r)*128 + j] = fmaxf(acc[r]+b, 0.f);
}

// ---------------- msg scatter: agg[dst] += ew * hh[src]
__global__ __launch_bounds__(256) void k_scatter(
    const int* __restrict__ ei, const float* __restrict__ ew,
    const float* __restrict__ hh, float* __restrict__ agg)
{
    size_t g = (size_t)blockIdx.x*256 + threadIdx.x;   // < T*E*128
    int ch = (int)(g & 127);
    int eg = (int)(g >> 7);        // t*E+e
    int t = eg >> 14;
    int e = eg & (Ee-1);
    int dst = ei[t*2*Ee + e];
    int src = ei[t*2*Ee + Ee + e];
    float w = ew[eg];
    float v = w * hh[((size_t)(t*Nn+src))*128 + ch];
    atomicAdd(&agg[((size_t)(t*Nn+dst))*128 + ch], v);
}

// ---------------- h2 = relu((hh+agg) @ W2[128,128] + b2)
__global__ __launch_bounds__(256) void k_wle2(
    const float* __restrict__ hh, const float* __restrict__ agg,
    const float* __restrict__ W2, const float* __restrict__ b2,
    float* __restrict__ h2)
{
    __shared__ float sx[16][128];
    int tid=threadIdx.x; int r0=blockIdx.x*16;
#pragma unroll
    for (int k=0;k<8;++k){
        int lin=k*256+tid;
        size_t gidx=(size_t)r0*128+lin;
        sx[lin>>7][lin&127]=hh[gidx]+agg[gidx];
    }
    __syncthreads();
    int j=tid&127; int rb=(tid>>7)*8;
    float acc[8];
#pragma unroll
    for(int r=0;r<8;++r)acc[r]=0.f;
    for(int i=0;i<128;i+=4){
        float w0=W2[(i+0)*128+j], w1=W2[(i+1)*128+j];
        float w2v=W2[(i+2)*128+j], w3=W2[(i+3)*128+j];
#pragma unroll
        for(int r=0;r<8;++r){
            float4 f=*(const float4*)&sx[rb+r][i];
            acc[r]+=f.x*w0+f.y*w1+f.z*w2v+f.w*w3;
        }
    }
    float b=b2[j];
#pragma unroll
    for(int r=0;r<8;++r) h2[(size_t)(r0+rb+r)*128+j]=fmaxf(acc[r]+b,0.f);
}

// ---------------- transpose W3 [128][128] -> w3t [j][i]
__global__ __launch_bounds__(256) void k_w3t(
    const float* __restrict__ W3, float* __restrict__ w3t)
{
    int lin = blockIdx.x*256 + threadIdx.x;   // < 16384
    int i = lin >> 7, j = lin & 127;
    w3t[j*128 + i] = W3[lin];
}

// ---------------- edge scores: s = relu((h2[a]*h2[b]) @ W3) . w4 + b4
// One edge per thread: ef[128] in registers, W3T rows broadcast from LDS.
__global__ __launch_bounds__(256, 2) void k_edge2(
    const int* __restrict__ ei, const float* __restrict__ h2,
    const float* __restrict__ w3t, const float* __restrict__ b3,
    const float* __restrict__ w4, const float* __restrict__ b4,
    float* __restrict__ sc)
{
    __shared__ float sw[128*128];
    int tid = threadIdx.x;
    int eg = blockIdx.x*256 + tid;            // < TE
    int t = eg >> 14, e = eg & (Ee-1);
    int a = ei[t*2*Ee + e], b = ei[t*2*Ee + Ee + e];
    const float4* __restrict__ pa = (const float4*)&h2[((size_t)(t*Nn+a))*128];
    const float4* __restrict__ pb = (const float4*)&h2[((size_t)(t*Nn+b))*128];

    float4 ef[32];
#pragma unroll
    for (int k=0;k<32;++k){
        float4 x = pa[k], y = pb[k];
        x.x*=y.x; x.y*=y.y; x.z*=y.z; x.w*=y.w;
        ef[k] = x;
    }

    // stage W3T (already transposed) linearly into LDS
#pragma unroll
    for (int k=0;k<16;++k)
        ((float4*)sw)[k*256+tid] = ((const float4*)w3t)[k*256+tid];
    __syncthreads();

    float s = b4[0];
    for (int j=0;j<128;++j){
        const float4* __restrict__ w = (const float4*)&sw[j*128];  // uniform: broadcast
        float a0=0.f,a1=0.f,a2=0.f,a3=0.f;
#pragma unroll
        for (int k=0;k<32;k+=4){
            float4 w0=w[k], w1=w[k+1], w2=w[k+2], w3v=w[k+3];
            a0 += ef[k  ].x*w0.x + ef[k  ].y*w0.y + ef[k  ].z*w0.z + ef[k  ].w*w0.w;
            a1 += ef[k+1].x*w1.x + ef[k+1].y*w1.y + ef[k+1].z*w1.z + ef[k+1].w*w1.w;
            a2 += ef[k+2].x*w2.x + ef[k+2].y*w2.y + ef[k+2].z*w2.z + ef[k+2].w*w2.w;
            a3 += ef[k+3].x*w3v.x + ef[k+3].y*w3v.y + ef[k+3].z*w3v.z + ef[k+3].w*w3v.w;
        }
        float acc = (a0+a1)+(a2+a3);
        s += fmaxf(acc + b3[j], 0.f) * w4[j];
    }
    sc[eg] = s;
}

// ---------------- densify with last-write-wins: tag pass then write pass
__global__ __launch_bounds__(256) void k_tag(const int* __restrict__ ei, int* __restrict__ tag)
{
    int g = blockIdx.x*256+threadIdx.x;        // < T*E
    int t = g>>14, e = g&(Ee-1);
    int a = ei[t*2*Ee + e], b = ei[t*2*Ee + Ee + e];
    atomicMax(&tag[t*NNc + a*Nn + b], g+1);
}

__global__ __launch_bounds__(256) void k_dense(
    const int* __restrict__ ei, const float* __restrict__ sc,
    const int* __restrict__ tag, float* __restrict__ dense)
{
    int g = blockIdx.x*256+threadIdx.x;
    int t = g>>14, e = g&(Ee-1);
    int a = ei[t*2*Ee + e], b = ei[t*2*Ee + Ee + e];
    int cell = t*NNc + a*Nn + b;
    if (tag[cell] == g+1) dense[cell] = sc[g];
}

// ---------------- SSM recurrence: only cells with an edge at t=T-1 have nonzero output
__global__ __launch_bounds__(256) void k_ssm(
    const int* __restrict__ ei, const float* __restrict__ dense,
    const float* __restrict__ W_in, const float* __restrict__ conv_w,
    const float* __restrict__ conv_b, const float* __restrict__ dt_bias,
    const float* __restrict__ A_log, const float* __restrict__ D_skip,
    const float* __restrict__ W_out, float* __restrict__ out)
{
    __shared__ float scw[132], scb[33], swin[35];
    int tid = threadIdx.x;
    if (tid < 132) scw[tid] = conv_w[tid];
    if (tid < 33)  scb[tid] = conv_b[tid];
    if (tid < 35)  swin[tid] = W_in[tid];
    __syncthreads();

    int e = blockIdx.x*256 + tid;              // < E
    int a = ei[7*2*Ee + e], b = ei[7*2*Ee + Ee + e];
    int cell = a*Nn + b;
    float x[8];
#pragma unroll
    for (int t=0;t<8;++t) x[t] = dense[t*NNc + cell];

    float A    = -expf(A_log[0]);
    float dtb  = dt_bias[0];
    float dsk  = D_skip[0];
    float wout = W_out[0];
    float win_z = swin[0], win_dt = swin[34];

    float ssm[16];
#pragma unroll
    for (int q=0;q<16;++q) ssm[q]=0.f;
    float h0=0.f,h1=0.f,h2v=0.f;
    float y=0.f;
    for (int t=0;t<8;++t){
        float xt = x[t];
        float act[33];
#pragma unroll
        for (int c=0;c<33;++c){
            float s = h0*scw[c*4+0] + h1*scw[c*4+1] + h2v*scw[c*4+2] + xt*scw[c*4+3];
            float pre = swin[1+c]*s + scb[c];
            act[c] = pre / (1.f + expf(-pre));
        }
        float x_ = act[0];
        float dtr = xt*win_dt + dtb;
        float dt  = (dtr > 20.f) ? dtr : log1pf(expf(dtr));
        float dA  = expf(dt*A);
        float dx  = dt*x_;
        float yv = 0.f;
#pragma unroll
        for (int q=0;q<16;++q){
            ssm[q] = ssm[q]*dA + dx*act[1+q];
            yv += ssm[q]*act[17+q];
        }
        yv += dsk*x_;
        float z = xt*win_z;
        yv *= z / (1.f + expf(-z));
        y = yv;
        h0=h1; h1=h2v; h2v=xt;
    }
    out[cell] = y*wout;
}

extern "C" void kernel_launch(void* const* d_in, const int* in_sizes, int n_in,
                              void* d_out, int out_size, void* d_ws, size_t ws_size,
                              hipStream_t stream)
{
    const int*   ei    = (const int*)d_in[0];
    const float* ew    = (const float*)d_in[1];
    const float* feats = (const float*)d_in[2];
    const float* noise = (const float*)d_in[3];
    const float* Wp1=(const float*)d_in[4];  const float* bp1=(const float*)d_in[5];
    const float* Wp2=(const float*)d_in[6];  const float* bp2=(const float*)d_in[7];
    const float* W1 =(const float*)d_in[8];  const float* b1 =(const float*)d_in[9];
    const float* W2 =(const float*)d_in[10]; const float* b2 =(const float*)d_in[11];
    const float* W3 =(const float*)d_in[12]; const float* b3 =(const float*)d_in[13];
    const float* w4 =(const float*)d_in[14]; const float* b4 =(const float*)d_in[15];
    const float* W_in  =(const float*)d_in[16]; const float* conv_w=(const float*)d_in[17];
    const float* conv_b=(const float*)d_in[18]; const float* dt_bias=(const float*)d_in[19];
    const float* A_log =(const float*)d_in[20]; const float* D_skip=(const float*)d_in[21];
    const float* W_out =(const float*)d_in[22];

    float* out = (float*)d_out;
    float* ws  = (float*)d_ws;
    float* emb   = ws;                      // T*N*80   = 327680
    float* hh    = emb   + 327680;          // T*N*128  = 524288
    float* agg   = hh    + 524288;          // 524288
    float* h2    = agg   + 524288;          // 524288
    float* sc    = h2    + 524288;          // T*E      = 131072
    float* dense = sc    + 131072;          // T*N*N    = 2097152
    int*   tag   = (int*)(dense + 2097152); // T*N*N ints
    float* w3t   = (float*)(tag + 2097152); // 16384

    hipMemsetAsync(agg,   0, (size_t)524288*4,  stream);
    hipMemsetAsync(dense, 0, (size_t)2097152*4, stream);
    hipMemsetAsync(tag,   0, (size_t)2097152*4, stream);
    hipMemsetAsync(out,   0, (size_t)262144*4,  stream);

    k_featproj<<<TNr/16, 256, 0, stream>>>(feats, noise, Wp1, bp1, Wp2, bp2, emb);
    k_wle1   <<<TNr/16, 256, 0, stream>>>(emb, W1, b1, hh);
    k_scatter<<<(Tt*Ee*128)/256, 256, 0, stream>>>(ei, ew, hh, agg);
    k_wle2   <<<TNr/16, 256, 0, stream>>>(hh, agg, W2, b2, h2);
    k_w3t    <<<64, 256, 0, stream>>>(W3, w3t);
    k_edge2  <<<TE/256, 256, 0, stream>>>(ei, h2, w3t, b3, w4, b4, sc);
    k_tag    <<<TE/256, 256, 0, stream>>>(ei, tag);
    k_dense  <<<TE/256, 256, 0, stream>>>(ei, sc, tag, dense);
    k_ssm    <<<Ee/256, 256, 0, stream>>>(ei, dense, W_in, conv_w, conv_b,
                                          dt_bias, A_log, D_skip, W_out, out);
}